// Round 15
// baseline (306.779 us; speedup 1.0000x reference)
//
#include <hip/hip_runtime.h>
#include <hip/hip_bf16.h>

#define N0 4096
#define N1 16384
#define HID 128
#define LAT 64
#define DIM 3
#define NAUG 21
#define JTOT 512    // xl(128) | xr(128) | lins(128) | pe(128)
#define NG 5        // k-groups (K padded 131->160)

typedef __attribute__((ext_vector_type(8))) short bf16x8;
typedef __attribute__((ext_vector_type(4))) float f32x4;

__device__ __constant__ int c_aug[NAUG] = {1,2,3,4,5,6,7,8,9,10,11,12,13,14,
                                           15,16,17,18,19,21,24};

__device__ __forceinline__ unsigned short f2bf(float v) {
    __hip_bfloat16 b = __float2bfloat16(v);
    return *reinterpret_cast<unsigned short*>(&b);
}

// ---------------------------------------------------------------------------
// Prep: Wswz B-fragments, bias_cat, Wt0, and the pos/zero (g=4) planes of
// BOTH ping-pong hswz buffers per graph (static per graph).
// Fragment mapping: hswz[((mt*5+g)*64+l)*8+j] = h[mt*16+(l&15)][g*32+(l>>4)*8+j]
// ---------------------------------------------------------------------------
#define WSWZ_PER_LAYER 81920   // 160*512
#define H0G4 131072            // (N0/16)*64*8
#define H1G4 524288            // (N1/16)*64*8
__global__ void prep_kernel(const float* __restrict__ Wl,
                            const float* __restrict__ Wr,
                            const float* __restrict__ We,
                            const float* __restrict__ linsW,
                            const float* __restrict__ bl,
                            const float* __restrict__ br,
                            const float* __restrict__ linsb,
                            const float* __restrict__ lin0W,
                            const float* __restrict__ pos0,
                            const float* __restrict__ pos1,
                            unsigned short* __restrict__ Wswz,
                            float* __restrict__ bias_cat,
                            float* __restrict__ Wt0,
                            unsigned short* __restrict__ hswz0A,
                            unsigned short* __restrict__ hswz0B,
                            unsigned short* __restrict__ hswz1A,
                            unsigned short* __restrict__ hswz1B) {
    int tid = blockIdx.x * blockDim.x + threadIdx.x;
    const int NSWZ = 4 * WSWZ_PER_LAYER;     // 327680
    const int B0 = NSWZ;                      // bias_cat start
    const int B1 = B0 + 4 * JTOT;             // Wt0 start
    const int B2 = B1 + 64 * 128;             // hswz0 g4 start
    const int B3 = B2 + H0G4;                 // hswz1 g4 start
    const int B4 = B3 + H1G4;
    if (tid < NSWZ) {
        int c = tid / WSWZ_PER_LAYER;
        int r = tid - c * WSWZ_PER_LAYER;    // ((nt*5+g)*64+l)*8+j
        int nt = r / 2560;
        int g  = (r / 512) % 5;
        int l  = (r / 8) % 64;
        int j  = r % 8;
        int k  = g * 32 + (l >> 4) * 8 + j;
        int n  = nt * 16 + (l & 15);
        float v = 0.0f;
        if (k < 131) {
            if (n < 128)      v = Wl[(c * 128 + n) * 131 + k];
            else if (n < 256) v = Wr[(c * 128 + (n - 128)) * 131 + k];
            else if (n < 384) v = linsW[(c * 128 + (n - 256)) * 131 + k];
            else              v = (k >= 128) ? We[(c * 128 + (n - 384)) * 3 + (k - 128)]
                                             : 0.0f;
        }
        Wswz[tid] = f2bf(v);
    } else if (tid < B1) {                   // bias_cat
        int idx = tid - B0;
        int c = idx / JTOT;
        int j = idx - c * JTOT;
        float v;
        if (j < 128)        v = bl[c * 128 + j];
        else if (j < 256)   v = br[c * 128 + (j - 128)];
        else if (j < 384)   v = linsb[c * 128 + (j - 256)];
        else                v = 0.0f;
        bias_cat[idx] = v;
    } else if (tid < B2) {                   // Wt0
        int idx = tid - B1;
        int k = idx / 128;
        int j = idx - k * 128;
        Wt0[idx] = lin0W[j * 64 + k];
    } else if (tid < B3) {                   // hswz0 g=4 plane (both buffers)
        int r = tid - B2;                    // (mt*64 + l)*8 + j
        int j = r & 7;
        int l = (r >> 3) & 63;
        int mt = r >> 9;
        int row = mt * 16 + (l & 15);
        int k = 128 + (l >> 4) * 8 + j;
        float v = (k < 131) ? pos0[row * 3 + (k - 128)] : 0.0f;
        unsigned short bv = f2bf(v);
        size_t idx = (size_t)((mt * 5 + 4) * 64 + l) * 8 + j;
        hswz0A[idx] = bv;
        hswz0B[idx] = bv;
    } else if (tid < B4) {                   // hswz1 g=4 plane (both buffers)
        int r = tid - B3;
        int j = r & 7;
        int l = (r >> 3) & 63;
        int mt = r >> 9;
        int row = mt * 16 + (l & 15);
        int k = 128 + (l >> 4) * 8 + j;
        float v = (k < 131) ? pos1[row * 3 + (k - 128)] : 0.0f;
        unsigned short bv = f2bf(v);
        size_t idx = (size_t)((mt * 5 + 4) * 64 + l) * 8 + j;
        hswz1A[idx] = bv;
        hswz1B[idx] = bv;
    }
}

// ---------------------------------------------------------------------------
// lin0: x0[n][j] = latent[n].lin0_W[j] + b[j], written straight into hswz0A
// ---------------------------------------------------------------------------
__global__ void lin0_kernel(const float* __restrict__ latent,
                            const float* __restrict__ Wt0,
                            const float* __restrict__ b,
                            unsigned short* __restrict__ hswz0) {
    __shared__ float lrow[64];
    int n = blockIdx.x;
    int j = threadIdx.x;
    if (j < 64) lrow[j] = latent[n * 64 + j];
    __syncthreads();
    float acc = b[j];
#pragma unroll 8
    for (int k = 0; k < 64; ++k) acc += lrow[k] * Wt0[k * 128 + j];
    int g = j >> 5, sub = (j >> 3) & 3, jj = j & 7;
    hswz0[(size_t)(((n >> 4) * 5 + g) * 64 + sub * 16 + (n & 15)) * 8 + jj] = f2bf(acc);
}

// ---------------------------------------------------------------------------
// FUSED layer kernel (v5): GEMM (MFMA, halo recompute) + GATv2 gather.
// Gather re-mapped to 8 lanes/node x 16 dims/lane (wave = 8 nodes; waves 0-1
// cover the 16-node tile, waves 2-3 exit after the barrier).  Rationale: the
// ~44 µs invariant across R9-R14 closes as DS-pipe ISSUE saturation
// (22 iters x (4 b128 + 4 shfl) per 4-node wave = ~1050 cyc/node of DS).
// New layout: 8 b128 reads serve 8 nodes and only 3 shuffle rounds ->
// ~30 DS-instr/node; work shifts to the 4x-wider VALU pipe.
// ---------------------------------------------------------------------------
#define WROW 40
#define FSTR 132
__global__ __launch_bounds__(256)
void fused_layer_kernel(const unsigned short* __restrict__ hswz,
                        const unsigned short* __restrict__ Wswz,
                        const float* __restrict__ bias_cat,
                        const float* __restrict__ att,
                        const float* __restrict__ bias,
                        float* __restrict__ linb,
                        float* __restrict__ xout,
                        unsigned short* __restrict__ hout,
                        int mode, int N) {
    __shared__ float xls_s[WROW][FSTR];
    __shared__ float pes_s[WROW][FSTR];
    __shared__ float xr_s[16][FSTR];

    int tid = threadIdx.x;
    int w = tid >> 6;
    int l = tid & 63;
    int quad = l >> 4, lcol = l & 15;
    int mt0 = blockIdx.x;           // center m-tile; n0 = mt0*16
    int n0 = mt0 * 16;
    int MT = N >> 4;

    // ---- GEMM phase (R14, unchanged) ----
    bf16x8 a[3][NG];
#pragma unroll
    for (int i = 0; i < 3; ++i) {
        int mt = mt0 - 2 + i;
        if (mt < 0) mt += MT;
#pragma unroll
        for (int g = 0; g < NG; ++g)
            a[i][g] = *(const bf16x8*)&hswz[(size_t)((mt * NG + g) * 64 + l) * 8];
    }

#pragma unroll
    for (int i = 0; i < 8; ++i) {
        int b = i * 4 + w;          // 0..31, wave-uniform
        int colbase = (b & 7) * 16;
        int ntw, kind;              // kind: 0 xl(3mt) 1 pe(3mt) 2 xr 3 lin
        if (b < 8)       { ntw = b;      kind = 0; }
        else if (b < 16) { ntw = 16 + b; kind = 1; }
        else if (b < 24) { ntw = b - 8;  kind = 2; }
        else             { ntw = b - 8;  kind = 3; }
        bf16x8 bf[NG];
#pragma unroll
        for (int g = 0; g < NG; ++g)
            bf[g] = *(const bf16x8*)&Wswz[(size_t)((ntw * NG + g) * 64 + l) * 8];
        float bv = bias_cat[ntw * 16 + lcol];
        if (kind < 2) {
            float (*dst)[FSTR] = (kind == 0) ? xls_s : pes_s;
#pragma unroll
            for (int m = 0; m < 3; ++m) {
                f32x4 c = {bv, bv, bv, bv};
#pragma unroll
                for (int g = 0; g < NG; ++g)
                    c = __builtin_amdgcn_mfma_f32_16x16x32_bf16(a[m][g], bf[g], c, 0, 0, 0);
                if (m == 0) {
                    if (quad >= 2) {
                        int w0 = (quad - 2) * 4;
#pragma unroll
                        for (int r = 0; r < 4; ++r) dst[w0 + r][colbase + lcol] = c[r];
                    }
                } else {
                    int w0 = m * 16 - 8 + quad * 4;
#pragma unroll
                    for (int r = 0; r < 4; ++r) dst[w0 + r][colbase + lcol] = c[r];
                }
            }
        } else if (kind == 2) {
            f32x4 c = {bv, bv, bv, bv};
#pragma unroll
            for (int g = 0; g < NG; ++g)
                c = __builtin_amdgcn_mfma_f32_16x16x32_bf16(a[2][g], bf[g], c, 0, 0, 0);
            int w0 = quad * 4;
#pragma unroll
            for (int r = 0; r < 4; ++r) xr_s[w0 + r][colbase + lcol] = c[r];
        } else {                    // lin -> global scratch (L2-resident)
            f32x4 c = {bv, bv, bv, bv};
#pragma unroll
            for (int g = 0; g < NG; ++g)
                c = __builtin_amdgcn_mfma_f32_16x16x32_bf16(a[2][g], bf[g], c, 0, 0, 0);
            int jj = colbase + lcol;
#pragma unroll
            for (int r = 0; r < 4; ++r)
                linb[(size_t)(n0 + quad * 4 + r) * 128 + jj] = c[r];
        }
    }
    __syncthreads();

    if (w >= 2) return;             // gather needs only 2 waves (8 nodes each)

    // ---- Gather phase: 8 lanes/node, 16 dims/lane ----
    int ln = l >> 3;                // node within wave: 0..7
    int t  = l & 7;                 // dim group: dims [t*16, t*16+16)
    int dl = w * 8 + ln;            // 0..15
    int d  = n0 + dl;
    int selfrow = dl + 24;
    int i0 = t * 16;

    float att16[16], base16[16], xld16[16], pesum16[16], o16[16];
#pragma unroll
    for (int v = 0; v < 4; ++v) {
        f32x4 av = *(const f32x4*)&att[i0 + v * 4];
        f32x4 xv = *(const f32x4*)&xls_s[selfrow][i0 + v * 4];
        f32x4 rv = *(const f32x4*)&xr_s[dl][i0 + v * 4];
        f32x4 pv = *(const f32x4*)&pes_s[selfrow][i0 + v * 4];
#pragma unroll
        for (int j = 0; j < 4; ++j) {
            att16[v * 4 + j]  = av[j];
            xld16[v * 4 + j]  = xv[j];
            base16[v * 4 + j] = rv[j] + pv[j];
            pesum16[v * 4 + j] = 0.0f;
            o16[v * 4 + j] = 0.0f;
        }
    }

    float m_run = -1e30f, den = 0.0f;

#pragma unroll
    for (int k = 0; k < NAUG; ++k) {
        int lr = selfrow - c_aug[k];
        float xls[16], pes[16];
#pragma unroll
        for (int v = 0; v < 4; ++v) {
            *(f32x4*)&xls[v * 4] = *(const f32x4*)&xls_s[lr][i0 + v * 4];
            *(f32x4*)&pes[v * 4] = *(const f32x4*)&pes_s[lr][i0 + v * 4];
        }
        float p = 0.0f;
#pragma unroll
        for (int j = 0; j < 16; ++j) {
            float mm = xls[j] + base16[j] - pes[j];
            mm = mm > 0.0f ? mm : 0.2f * mm;
            p = fmaf(att16[j], mm, p);
            pesum16[j] += pes[j];
        }
        p += __shfl_xor(p, 1, 64);
        p += __shfl_xor(p, 2, 64);
        p += __shfl_xor(p, 4, 64);
        float mn = fmaxf(m_run, p);
        float corr = __expf(m_run - mn);
        float wgt = __expf(p - mn);
        den = den * corr + wgt;
#pragma unroll
        for (int j = 0; j < 16; ++j) o16[j] = fmaf(o16[j], corr, wgt * xls[j]);
        m_run = mn;
    }
    {   // self loop: eattr = ped - mean(pes); m = xld + base - mean
        const float inv21 = 1.0f / 21.0f;
        float p = 0.0f;
#pragma unroll
        for (int j = 0; j < 16; ++j) {
            float mm = xld16[j] + base16[j] - pesum16[j] * inv21;
            mm = mm > 0.0f ? mm : 0.2f * mm;
            p = fmaf(att16[j], mm, p);
        }
        p += __shfl_xor(p, 1, 64);
        p += __shfl_xor(p, 2, 64);
        p += __shfl_xor(p, 4, 64);
        float mn = fmaxf(m_run, p);
        float corr = __expf(m_run - mn);
        float wgt = __expf(p - mn);
        den = den * corr + wgt;
#pragma unroll
        for (int j = 0; j < 16; ++j) o16[j] = fmaf(o16[j], corr, wgt * xld16[j]);
    }

    float inv = 1.0f / (den + 1e-16f);
    float res[16];
#pragma unroll
    for (int v = 0; v < 4; ++v) {
        f32x4 bv = *(const f32x4*)&bias[i0 + v * 4];
        f32x4 lv = *(const f32x4*)&linb[(size_t)d * 128 + i0 + v * 4];
#pragma unroll
        for (int j = 0; j < 4; ++j) {
            float vv = o16[v * 4 + j] * inv + bv[j];
            vv = vv > 0.0f ? vv : __expf(vv) - 1.0f;
            res[v * 4 + j] = vv + lv[j];
        }
    }

    if (mode == 0) {
        float* p = &xout[(size_t)d * 128 + i0];
#pragma unroll
        for (int v = 0; v < 4; ++v)
            *(f32x4*)(p + v * 4) = *(f32x4*)&res[v * 4];
    } else {
        unsigned short ob[16];
#pragma unroll
        for (int j = 0; j < 16; ++j) ob[j] = f2bf(res[j]);
#pragma unroll
        for (int h = 0; h < 2; ++h) {
            int k0 = i0 + h * 8;
            int g = k0 >> 5;
            int sub = (k0 & 31) >> 3;
            *(bf16x8*)&hout[(size_t)(((d >> 4) * 5 + g) * 64 + sub * 16 + (d & 15)) * 8]
                = *(bf16x8*)&ob[h * 8];
        }
    }
}

// ---------------------------------------------------------------------------
// knn: branchless top-3 with exact f32 distances (R8, unchanged).
// ---------------------------------------------------------------------------
#define KCH 64
#define KCS 64    // 4096 / 64
#define YPT 4

__global__ __launch_bounds__(256)
void knn_part_kernel(const float* __restrict__ pos0, const float* __restrict__ pos1,
                     float* __restrict__ pb_d, int* __restrict__ pb_i) {
    __shared__ float4 sx[KCS];   // (x, y, z, |x|^2)
    int tid = threadIdx.x;
    int chunk = blockIdx.y;
    if (tid < KCS) {
        const float* p = &pos0[(chunk * KCS + tid) * 3];
        float x = p[0], y = p[1], z = p[2];
        sx[tid] = make_float4(x, y, z, x * x + y * y + z * z);
    }
    __syncthreads();
    int ybase = blockIdx.x * (256 * YPT) + tid;
    float m2y[YPT][3], sy[YPT];
#pragma unroll
    for (int u = 0; u < YPT; ++u) {
        int y = ybase + u * 256;
        float p0 = pos1[y * 3], p1 = pos1[y * 3 + 1], p2 = pos1[y * 3 + 2];
        m2y[u][0] = -2.0f * p0; m2y[u][1] = -2.0f * p1; m2y[u][2] = -2.0f * p2;
        sy[u] = p0 * p0 + p1 * p1 + p2 * p2;
    }
    float bd0[YPT], bd1[YPT], bd2[YPT];
    int   bi0[YPT], bi1[YPT], bi2[YPT];
#pragma unroll
    for (int u = 0; u < YPT; ++u) {
        bd0[u] = 1e30f; bd1[u] = 1e30f; bd2[u] = 1e30f;
        bi0[u] = 0; bi1[u] = 0; bi2[u] = 0;
    }

    int gbase = chunk * KCS;
#pragma unroll 4
    for (int i = 0; i < KCS; i += 4) {
        float4 s[4];
#pragma unroll
        for (int v = 0; v < 4; ++v) s[v] = sx[i + v];
#pragma unroll
        for (int v = 0; v < 4; ++v) {
            int gi = gbase + i + v;
#pragma unroll
            for (int u = 0; u < YPT; ++u) {
                float t = fmaf(m2y[u][0], s[v].x, s[v].w);
                t = fmaf(m2y[u][1], s[v].y, t);
                t = fmaf(m2y[u][2], s[v].z, t);
                t += sy[u];
                bool c0 = t < bd0[u];
                bool c1 = t < bd1[u];
                bool c2 = t < bd2[u];
                float n0 = fminf(bd0[u], t);
                float n1 = __builtin_amdgcn_fmed3f(bd0[u], bd1[u], t);
                float n2 = __builtin_amdgcn_fmed3f(bd1[u], bd2[u], t);
                int j0 = c0 ? gi : bi0[u];
                int j1 = c0 ? bi0[u] : (c1 ? gi : bi1[u]);
                int j2 = c1 ? bi1[u] : (c2 ? gi : bi2[u]);
                bd0[u] = n0; bd1[u] = n1; bd2[u] = n2;
                bi0[u] = j0; bi1[u] = j1; bi2[u] = j2;
            }
        }
    }
#pragma unroll
    for (int u = 0; u < YPT; ++u) {
        int y = ybase + u * 256;
        int base = (chunk * N1 + y) * 3;
        pb_d[base] = bd0[u]; pb_d[base + 1] = bd1[u]; pb_d[base + 2] = bd2[u];
        pb_i[base] = bi0[u]; pb_i[base + 1] = bi1[u]; pb_i[base + 2] = bi2[u];
    }
}

__global__ __launch_bounds__(256)
void knn_merge_kernel(const float* __restrict__ pb_d, const int* __restrict__ pb_i,
                      int* __restrict__ knn_idx, float* __restrict__ knn_w) {
    int y = blockIdx.x * 256 + threadIdx.x;
    float bd0 = 1e30f, bd1 = 1e30f, bd2 = 1e30f;
    int bi0 = 0, bi1 = 0, bi2 = 0;
    for (int c = 0; c < KCH; ++c) {
        int base = (c * N1 + y) * 3;
#pragma unroll
        for (int t3 = 0; t3 < 3; ++t3) {
            float t = pb_d[base + t3];
            int gi = pb_i[base + t3];
            bool c0 = t < bd0;
            bool c1 = t < bd1;
            bool c2 = t < bd2;
            float n0 = fminf(bd0, t);
            float n1 = __builtin_amdgcn_fmed3f(bd0, bd1, t);
            float n2 = __builtin_amdgcn_fmed3f(bd1, bd2, t);
            int j0 = c0 ? gi : bi0;
            int j1 = c0 ? bi0 : (c1 ? gi : bi1);
            int j2 = c1 ? bi1 : (c2 ? gi : bi2);
            bd0 = n0; bd1 = n1; bd2 = n2;
            bi0 = j0; bi1 = j1; bi2 = j2;
        }
    }
    knn_idx[y * 3]     = bi0;
    knn_idx[y * 3 + 1] = bi1;
    knn_idx[y * 3 + 2] = bi2;
    knn_w[y * 3]     = 1.0f / fmaxf(bd0, 1e-16f);
    knn_w[y * 3 + 1] = 1.0f / fmaxf(bd1, 1e-16f);
    knn_w[y * 3 + 2] = 1.0f / fmaxf(bd2, 1e-16f);
}

// ---------------------------------------------------------------------------
// interp: writes bf16 A-fragments for layer-2 GEMM directly.
// ---------------------------------------------------------------------------
__global__ __launch_bounds__(256)
void interp_kernel(const float* __restrict__ x0, const int* __restrict__ knn_idx,
                   const float* __restrict__ knn_w, unsigned short* __restrict__ hswz) {
    int wave = threadIdx.x >> 6;
    int lane = threadIdx.x & 63;
    int y = blockIdx.x * 4 + wave;
    int i0 = 2 * lane;
    float w0 = knn_w[y * 3], w1 = knn_w[y * 3 + 1], w2 = knn_w[y * 3 + 2];
    int j0 = knn_idx[y * 3], j1 = knn_idx[y * 3 + 1], j2 = knn_idx[y * 3 + 2];
    float inv = 1.0f / (w0 + w1 + w2);
    float2 a = *(const float2*)&x0[(size_t)j0 * 128 + i0];
    float2 b = *(const float2*)&x0[(size_t)j1 * 128 + i0];
    float2 c = *(const float2*)&x0[(size_t)j2 * 128 + i0];
    float rx = (w0 * a.x + w1 * b.x + w2 * c.x) * inv;
    float ry = (w0 * a.y + w1 * b.y + w2 * c.y) * inv;
    unsigned int packed = (unsigned int)f2bf(rx) | ((unsigned int)f2bf(ry) << 16);
    int g = i0 >> 5, sub = (i0 >> 3) & 3, jj = i0 & 7;
    size_t idx = (size_t)((((y >> 4) * 5 + g) * 64) + sub * 16 + (y & 15)) * 8 + jj;
    *(unsigned int*)&hswz[idx] = packed;
}

// ---------------------------------------------------------------------------
// Output head: out[y] = [x1[y] | pos1[y]] @ out_W.T + out_b. One wave per y.
// ---------------------------------------------------------------------------
__global__ __launch_bounds__(256)
void out_kernel(const float* __restrict__ x1, const float* __restrict__ pos1,
                const float* __restrict__ W, const float* __restrict__ b,
                float* __restrict__ out) {
    int wave = threadIdx.x >> 6;
    int lane = threadIdx.x & 63;
    int y = blockIdx.x * 4 + wave;
    float h0 = x1[(size_t)y * 128 + lane];
    float h1 = x1[(size_t)y * 128 + 64 + lane];
    float acc[3];
#pragma unroll
    for (int o = 0; o < 3; ++o) {
        float p = h0 * W[o * 131 + lane] + h1 * W[o * 131 + 64 + lane];
#pragma unroll
        for (int off = 1; off < 64; off <<= 1) p += __shfl_xor(p, off, 64);
        acc[o] = p;
    }
    if (lane == 0) {
        float p0 = pos1[y * 3], p1 = pos1[y * 3 + 1], p2 = pos1[y * 3 + 2];
#pragma unroll
        for (int o = 0; o < 3; ++o) {
            out[y * 3 + o] = acc[o] + b[o] + p0 * W[o * 131 + 128]
                           + p1 * W[o * 131 + 129] + p2 * W[o * 131 + 130];
        }
    }
}

// ---------------------------------------------------------------------------
extern "C" void kernel_launch(void* const* d_in, const int* in_sizes, int n_in,
                              void* d_out, int out_size, void* d_ws, size_t ws_size,
                              hipStream_t stream) {
    (void)in_sizes; (void)n_in; (void)out_size; (void)ws_size;
    const float* latent   = (const float*)d_in[0];
    const float* pos0     = (const float*)d_in[1];
    const float* pos1     = (const float*)d_in[2];
    const float* conv_Wl  = (const float*)d_in[5];
    const float* conv_bl  = (const float*)d_in[6];
    const float* conv_Wr  = (const float*)d_in[7];
    const float* conv_br  = (const float*)d_in[8];
    const float* conv_We  = (const float*)d_in[9];
    const float* conv_att = (const float*)d_in[10];
    const float* conv_bias= (const float*)d_in[11];
    const float* lin0_W   = (const float*)d_in[12];
    const float* lin0_b   = (const float*)d_in[13];
    const float* lins_W   = (const float*)d_in[14];
    const float* lins_b   = (const float*)d_in[15];
    const float* out_W    = (const float*)d_in[16];
    const float* out_b    = (const float*)d_in[17];
    float* out = (float*)d_out;

    char* ws = (char*)d_ws;
    unsigned short* Wswz = (unsigned short*)ws; ws += (size_t)4 * WSWZ_PER_LAYER * 2;
    float* bias_cat = (float*)ws;  ws += (size_t)4 * JTOT * 4;
    float* Wt0      = (float*)ws;  ws += (size_t)64 * 128 * 4;
    unsigned short* hswz0A = (unsigned short*)ws; ws += (size_t)(N0 / 16) * NG * 64 * 8 * 2;
    unsigned short* hswz0B = (unsigned short*)ws; ws += (size_t)(N0 / 16) * NG * 64 * 8 * 2;
    unsigned short* hswz1A = (unsigned short*)ws; ws += (size_t)(N1 / 16) * NG * 64 * 8 * 2;
    unsigned short* hswz1B = (unsigned short*)ws; ws += (size_t)(N1 / 16) * NG * 64 * 8 * 2;
    float* bufA     = (float*)ws;  ws += (size_t)N0 * 128 * 4;
    float* bufB     = (float*)ws;  ws += (size_t)N1 * 128 * 4;
    float* linb     = (float*)ws;  ws += (size_t)N1 * 128 * 4;   // lin scratch
    float* pb_d     = (float*)ws;  ws += (size_t)KCH * N1 * 3 * 4;
    int*   pb_i     = (int*)ws;    ws += (size_t)KCH * N1 * 3 * 4;
    int*   knn_idx  = (int*)ws;    ws += (size_t)N1 * 3 * 4;
    float* knn_w    = (float*)ws;  ws += (size_t)N1 * 3 * 4;

    prep_kernel<<<3880, 256, 0, stream>>>(conv_Wl, conv_Wr, conv_We, lins_W,
                                          conv_bl, conv_br, lins_b, lin0_W,
                                          pos0, pos1,
                                          Wswz, bias_cat, Wt0,
                                          hswz0A, hswz0B, hswz1A, hswz1B);
    lin0_kernel<<<N0, 128, 0, stream>>>(latent, Wt0, lin0_b, hswz0A);

    // knn chain is independent - launch early
    knn_part_kernel<<<dim3(N1 / (256 * YPT), KCH), 256, 0, stream>>>(pos0, pos1, pb_d, pb_i);
    knn_merge_kernel<<<N1 / 256, 256, 0, stream>>>(pb_d, pb_i, knn_idx, knn_w);

    // layer 0: A -> B (bf16 frags);  layer 1: B -> bufA (f32)
    fused_layer_kernel<<<N0 / 16, 256, 0, stream>>>(
        hswz0A, Wswz + (size_t)0 * WSWZ_PER_LAYER, bias_cat + 0 * JTOT,
        conv_att + 0 * 128, conv_bias + 0 * 128, linb, nullptr, hswz0B, 1, N0);
    fused_layer_kernel<<<N0 / 16, 256, 0, stream>>>(
        hswz0B, Wswz + (size_t)1 * WSWZ_PER_LAYER, bias_cat + 1 * JTOT,
        conv_att + 1 * 128, conv_bias + 1 * 128, linb, bufA, nullptr, 0, N0);

    interp_kernel<<<N1 / 4, 256, 0, stream>>>(bufA, knn_idx, knn_w, hswz1A);

    // layer 2: A -> B;  layer 3: B -> bufB (f32)
    fused_layer_kernel<<<N1 / 16, 256, 0, stream>>>(
        hswz1A, Wswz + (size_t)2 * WSWZ_PER_LAYER, bias_cat + 2 * JTOT,
        conv_att + 2 * 128, conv_bias + 2 * 128, linb, nullptr, hswz1B, 1, N1);
    fused_layer_kernel<<<N1 / 16, 256, 0, stream>>>(
        hswz1B, Wswz + (size_t)3 * WSWZ_PER_LAYER, bias_cat + 3 * JTOT,
        conv_att + 3 * 128, conv_bias + 3 * 128, linb, bufB, nullptr, 0, N1);

    out_kernel<<<N1 / 4, 256, 0, stream>>>(bufB, pos1, out_W, out_b, out);
}

// Round 16
// 258.230 us; speedup vs baseline: 1.1880x; 1.1880x over previous
//
#include <hip/hip_runtime.h>
#include <hip/hip_bf16.h>

#define N0 4096
#define N1 16384
#define HID 128
#define LAT 64
#define DIM 3
#define NAUG 21
#define JTOT 512    // xl(128) | xr(128) | lins(128) | pe(128)
#define NG 5        // k-groups (K padded 131->160)

typedef __attribute__((ext_vector_type(8))) short bf16x8;
typedef __attribute__((ext_vector_type(4))) float f32x4;

__device__ __constant__ int c_aug[NAUG] = {1,2,3,4,5,6,7,8,9,10,11,12,13,14,
                                           15,16,17,18,19,21,24};

__device__ __forceinline__ unsigned short f2bf(float v) {
    __hip_bfloat16 b = __float2bfloat16(v);
    return *reinterpret_cast<unsigned short*>(&b);
}

// ---------------------------------------------------------------------------
// Prep: Wswz B-fragments, bias_cat, Wt0, and the pos/zero (g=4) planes of
// BOTH ping-pong hswz buffers per graph (static per graph).
// Fragment mapping: hswz[((mt*5+g)*64+l)*8+j] = h[mt*16+(l&15)][g*32+(l>>4)*8+j]
// ---------------------------------------------------------------------------
#define WSWZ_PER_LAYER 81920   // 160*512
#define H0G4 131072            // (N0/16)*64*8
#define H1G4 524288            // (N1/16)*64*8
__global__ void prep_kernel(const float* __restrict__ Wl,
                            const float* __restrict__ Wr,
                            const float* __restrict__ We,
                            const float* __restrict__ linsW,
                            const float* __restrict__ bl,
                            const float* __restrict__ br,
                            const float* __restrict__ linsb,
                            const float* __restrict__ lin0W,
                            const float* __restrict__ pos0,
                            const float* __restrict__ pos1,
                            unsigned short* __restrict__ Wswz,
                            float* __restrict__ bias_cat,
                            float* __restrict__ Wt0,
                            unsigned short* __restrict__ hswz0A,
                            unsigned short* __restrict__ hswz0B,
                            unsigned short* __restrict__ hswz1A,
                            unsigned short* __restrict__ hswz1B) {
    int tid = blockIdx.x * blockDim.x + threadIdx.x;
    const int NSWZ = 4 * WSWZ_PER_LAYER;     // 327680
    const int B0 = NSWZ;                      // bias_cat start
    const int B1 = B0 + 4 * JTOT;             // Wt0 start
    const int B2 = B1 + 64 * 128;             // hswz0 g4 start
    const int B3 = B2 + H0G4;                 // hswz1 g4 start
    const int B4 = B3 + H1G4;
    if (tid < NSWZ) {
        int c = tid / WSWZ_PER_LAYER;
        int r = tid - c * WSWZ_PER_LAYER;    // ((nt*5+g)*64+l)*8+j
        int nt = r / 2560;
        int g  = (r / 512) % 5;
        int l  = (r / 8) % 64;
        int j  = r % 8;
        int k  = g * 32 + (l >> 4) * 8 + j;
        int n  = nt * 16 + (l & 15);
        float v = 0.0f;
        if (k < 131) {
            if (n < 128)      v = Wl[(c * 128 + n) * 131 + k];
            else if (n < 256) v = Wr[(c * 128 + (n - 128)) * 131 + k];
            else if (n < 384) v = linsW[(c * 128 + (n - 256)) * 131 + k];
            else              v = (k >= 128) ? We[(c * 128 + (n - 384)) * 3 + (k - 128)]
                                             : 0.0f;
        }
        Wswz[tid] = f2bf(v);
    } else if (tid < B1) {                   // bias_cat
        int idx = tid - B0;
        int c = idx / JTOT;
        int j = idx - c * JTOT;
        float v;
        if (j < 128)        v = bl[c * 128 + j];
        else if (j < 256)   v = br[c * 128 + (j - 128)];
        else if (j < 384)   v = linsb[c * 128 + (j - 256)];
        else                v = 0.0f;
        bias_cat[idx] = v;
    } else if (tid < B2) {                   // Wt0
        int idx = tid - B1;
        int k = idx / 128;
        int j = idx - k * 128;
        Wt0[idx] = lin0W[j * 64 + k];
    } else if (tid < B3) {                   // hswz0 g=4 plane (both buffers)
        int r = tid - B2;                    // (mt*64 + l)*8 + j
        int j = r & 7;
        int l = (r >> 3) & 63;
        int mt = r >> 9;
        int row = mt * 16 + (l & 15);
        int k = 128 + (l >> 4) * 8 + j;
        float v = (k < 131) ? pos0[row * 3 + (k - 128)] : 0.0f;
        unsigned short bv = f2bf(v);
        size_t idx = (size_t)((mt * 5 + 4) * 64 + l) * 8 + j;
        hswz0A[idx] = bv;
        hswz0B[idx] = bv;
    } else if (tid < B4) {                   // hswz1 g=4 plane (both buffers)
        int r = tid - B3;
        int j = r & 7;
        int l = (r >> 3) & 63;
        int mt = r >> 9;
        int row = mt * 16 + (l & 15);
        int k = 128 + (l >> 4) * 8 + j;
        float v = (k < 131) ? pos1[row * 3 + (k - 128)] : 0.0f;
        unsigned short bv = f2bf(v);
        size_t idx = (size_t)((mt * 5 + 4) * 64 + l) * 8 + j;
        hswz1A[idx] = bv;
        hswz1B[idx] = bv;
    }
}

// ---------------------------------------------------------------------------
// lin0: x0[n][j] = latent[n].lin0_W[j] + b[j], written straight into hswz0A
// ---------------------------------------------------------------------------
__global__ void lin0_kernel(const float* __restrict__ latent,
                            const float* __restrict__ Wt0,
                            const float* __restrict__ b,
                            unsigned short* __restrict__ hswz0) {
    __shared__ float lrow[64];
    int n = blockIdx.x;
    int j = threadIdx.x;
    if (j < 64) lrow[j] = latent[n * 64 + j];
    __syncthreads();
    float acc = b[j];
#pragma unroll 8
    for (int k = 0; k < 64; ++k) acc += lrow[k] * Wt0[k * 128 + j];
    int g = j >> 5, sub = (j >> 3) & 3, jj = j & 7;
    hswz0[(size_t)(((n >> 4) * 5 + g) * 64 + sub * 16 + (n & 15)) * 8 + jj] = f2bf(acc);
}

// ---------------------------------------------------------------------------
// FUSED layer kernel (v6 = R14 + max-free softmax).
// R15 measured time ∝ 1/waves (latency-bound).  The online-softmax rescale
// (m_run -> exp -> den/o) was a ~200-cyc loop-carried chain x 22 iters; the
// max-free form (softmax is shift-invariant; scores are O(1) here) makes
// every iteration's FMA+shuffle+exp chain independent -> pipelinable.
// ---------------------------------------------------------------------------
#define WROW 40
#define FSTR 132
__global__ __launch_bounds__(256)
void fused_layer_kernel(const unsigned short* __restrict__ hswz,
                        const unsigned short* __restrict__ Wswz,
                        const float* __restrict__ bias_cat,
                        const float* __restrict__ att,
                        const float* __restrict__ bias,
                        float* __restrict__ linb,
                        float* __restrict__ xout,
                        unsigned short* __restrict__ hout,
                        int mode, int N) {
    __shared__ float xls_s[WROW][FSTR];
    __shared__ float pes_s[WROW][FSTR];
    __shared__ float xr_s[16][FSTR];

    int tid = threadIdx.x;
    int w = tid >> 6;
    int l = tid & 63;
    int quad = l >> 4, lcol = l & 15;
    int mt0 = blockIdx.x;           // center m-tile; n0 = mt0*16
    int n0 = mt0 * 16;
    int MT = N >> 4;

    // ---- GEMM phase (R14, unchanged) ----
    bf16x8 a[3][NG];
#pragma unroll
    for (int i = 0; i < 3; ++i) {
        int mt = mt0 - 2 + i;
        if (mt < 0) mt += MT;
#pragma unroll
        for (int g = 0; g < NG; ++g)
            a[i][g] = *(const bf16x8*)&hswz[(size_t)((mt * NG + g) * 64 + l) * 8];
    }

#pragma unroll
    for (int i = 0; i < 8; ++i) {
        int b = i * 4 + w;          // 0..31, wave-uniform
        int colbase = (b & 7) * 16;
        int ntw, kind;              // kind: 0 xl(3mt) 1 pe(3mt) 2 xr 3 lin
        if (b < 8)       { ntw = b;      kind = 0; }
        else if (b < 16) { ntw = 16 + b; kind = 1; }
        else if (b < 24) { ntw = b - 8;  kind = 2; }
        else             { ntw = b - 8;  kind = 3; }
        bf16x8 bf[NG];
#pragma unroll
        for (int g = 0; g < NG; ++g)
            bf[g] = *(const bf16x8*)&Wswz[(size_t)((ntw * NG + g) * 64 + l) * 8];
        float bv = bias_cat[ntw * 16 + lcol];
        if (kind < 2) {
            float (*dst)[FSTR] = (kind == 0) ? xls_s : pes_s;
#pragma unroll
            for (int m = 0; m < 3; ++m) {
                f32x4 c = {bv, bv, bv, bv};
#pragma unroll
                for (int g = 0; g < NG; ++g)
                    c = __builtin_amdgcn_mfma_f32_16x16x32_bf16(a[m][g], bf[g], c, 0, 0, 0);
                if (m == 0) {
                    if (quad >= 2) {
                        int w0 = (quad - 2) * 4;
#pragma unroll
                        for (int r = 0; r < 4; ++r) dst[w0 + r][colbase + lcol] = c[r];
                    }
                } else {
                    int w0 = m * 16 - 8 + quad * 4;
#pragma unroll
                    for (int r = 0; r < 4; ++r) dst[w0 + r][colbase + lcol] = c[r];
                }
            }
        } else if (kind == 2) {
            f32x4 c = {bv, bv, bv, bv};
#pragma unroll
            for (int g = 0; g < NG; ++g)
                c = __builtin_amdgcn_mfma_f32_16x16x32_bf16(a[2][g], bf[g], c, 0, 0, 0);
            int w0 = quad * 4;
#pragma unroll
            for (int r = 0; r < 4; ++r) xr_s[w0 + r][colbase + lcol] = c[r];
        } else {                    // lin -> global scratch (L2-resident)
            f32x4 c = {bv, bv, bv, bv};
#pragma unroll
            for (int g = 0; g < NG; ++g)
                c = __builtin_amdgcn_mfma_f32_16x16x32_bf16(a[2][g], bf[g], c, 0, 0, 0);
            int jj = colbase + lcol;
#pragma unroll
            for (int r = 0; r < 4; ++r)
                linb[(size_t)(n0 + quad * 4 + r) * 128 + jj] = c[r];
        }
    }
    __syncthreads();

    // ---- Gather phase (max-free softmax) ----
    int q = l >> 4;
    int t = l & 15;
    int dl = w * 4 + q;             // 0..15
    int d = n0 + dl;
    int selfrow = dl + 24;
    int i0 = t * 8;

    // issue lin load early: latency hides under the 21-iteration loop
    f32x4 linv0 = *(const f32x4*)&linb[(size_t)d * 128 + i0];
    f32x4 linv1 = *(const f32x4*)&linb[(size_t)d * 128 + i0 + 4];

    float att8[8], base[8], xld[8], pesum[8], o[8];
    {
        f32x4 a0 = *(const f32x4*)&att[i0];
        f32x4 a1 = *(const f32x4*)&att[i0 + 4];
        f32x4 r0 = *(const f32x4*)&xr_s[dl][i0];
        f32x4 r1 = *(const f32x4*)&xr_s[dl][i0 + 4];
        f32x4 x0 = *(const f32x4*)&xls_s[selfrow][i0];
        f32x4 x1 = *(const f32x4*)&xls_s[selfrow][i0 + 4];
        f32x4 p0 = *(const f32x4*)&pes_s[selfrow][i0];
        f32x4 p1 = *(const f32x4*)&pes_s[selfrow][i0 + 4];
#pragma unroll
        for (int j = 0; j < 4; ++j) {
            att8[j] = a0[j];     att8[j + 4] = a1[j];
            xld[j]  = x0[j];     xld[j + 4]  = x1[j];
            base[j] = r0[j] + p0[j];
            base[j + 4] = r1[j] + p1[j];
            pesum[j] = 0.0f;     pesum[j + 4] = 0.0f;
            o[j] = 0.0f;         o[j + 4] = 0.0f;
        }
    }

    float den = 0.0f;

#pragma unroll
    for (int k = 0; k < NAUG; ++k) {
        int lr = selfrow - c_aug[k];
        float xls[8], pes[8];
        *(f32x4*)&xls[0] = *(const f32x4*)&xls_s[lr][i0];
        *(f32x4*)&xls[4] = *(const f32x4*)&xls_s[lr][i0 + 4];
        *(f32x4*)&pes[0] = *(const f32x4*)&pes_s[lr][i0];
        *(f32x4*)&pes[4] = *(const f32x4*)&pes_s[lr][i0 + 4];
        float p = 0.0f;
#pragma unroll
        for (int j = 0; j < 8; ++j) {
            float mm = xls[j] + base[j] - pes[j];
            mm = mm > 0.0f ? mm : 0.2f * mm;
            p = fmaf(att8[j], mm, p);
            pesum[j] += pes[j];
        }
        p += __shfl_xor(p, 1, 64);
        p += __shfl_xor(p, 2, 64);
        p += __shfl_xor(p, 4, 64);
        p += __shfl_xor(p, 8, 64);
        float wgt = __expf(p);
        den += wgt;
#pragma unroll
        for (int j = 0; j < 8; ++j) o[j] = fmaf(wgt, xls[j], o[j]);
    }
    {   // self loop: eattr = ped - mean(pes); m = xld + base - mean
        const float inv21 = 1.0f / 21.0f;
        float p = 0.0f;
#pragma unroll
        for (int j = 0; j < 8; ++j) {
            float mm = xld[j] + base[j] - pesum[j] * inv21;
            mm = mm > 0.0f ? mm : 0.2f * mm;
            p = fmaf(att8[j], mm, p);
        }
        p += __shfl_xor(p, 1, 64);
        p += __shfl_xor(p, 2, 64);
        p += __shfl_xor(p, 4, 64);
        p += __shfl_xor(p, 8, 64);
        float wgt = __expf(p);
        den += wgt;
#pragma unroll
        for (int j = 0; j < 8; ++j) o[j] = fmaf(wgt, xld[j], o[j]);
    }

    float inv = 1.0f / (den + 1e-16f);
    float res[8];
    {
        f32x4 b0 = *(const f32x4*)&bias[i0];
        f32x4 b1 = *(const f32x4*)&bias[i0 + 4];
#pragma unroll
        for (int j = 0; j < 8; ++j) {
            float v = o[j] * inv + (j < 4 ? b0[j] : b1[j - 4]);
            v = v > 0.0f ? v : __expf(v) - 1.0f;
            res[j] = v + (j < 4 ? linv0[j] : linv1[j - 4]);
        }
    }

    if (mode == 0) {
        float* p = &xout[(size_t)d * 128 + i0];
        *(f32x4*)p       = *(f32x4*)&res[0];
        *(f32x4*)(p + 4) = *(f32x4*)&res[4];
    } else {
        unsigned short ob[8];
#pragma unroll
        for (int j = 0; j < 8; ++j) ob[j] = f2bf(res[j]);
        int g = t >> 2, sub = t & 3;
        *(bf16x8*)&hout[(size_t)((((d >> 4) * 5 + g) * 64) + sub * 16 + (d & 15)) * 8] = *(bf16x8*)ob;
    }
}

// ---------------------------------------------------------------------------
// knn: branchless top-3 with exact f32 distances (R8, unchanged).
// ---------------------------------------------------------------------------
#define KCH 64
#define KCS 64    // 4096 / 64
#define YPT 4

__global__ __launch_bounds__(256)
void knn_part_kernel(const float* __restrict__ pos0, const float* __restrict__ pos1,
                     float* __restrict__ pb_d, int* __restrict__ pb_i) {
    __shared__ float4 sx[KCS];   // (x, y, z, |x|^2)
    int tid = threadIdx.x;
    int chunk = blockIdx.y;
    if (tid < KCS) {
        const float* p = &pos0[(chunk * KCS + tid) * 3];
        float x = p[0], y = p[1], z = p[2];
        sx[tid] = make_float4(x, y, z, x * x + y * y + z * z);
    }
    __syncthreads();
    int ybase = blockIdx.x * (256 * YPT) + tid;
    float m2y[YPT][3], sy[YPT];
#pragma unroll
    for (int u = 0; u < YPT; ++u) {
        int y = ybase + u * 256;
        float p0 = pos1[y * 3], p1 = pos1[y * 3 + 1], p2 = pos1[y * 3 + 2];
        m2y[u][0] = -2.0f * p0; m2y[u][1] = -2.0f * p1; m2y[u][2] = -2.0f * p2;
        sy[u] = p0 * p0 + p1 * p1 + p2 * p2;
    }
    float bd0[YPT], bd1[YPT], bd2[YPT];
    int   bi0[YPT], bi1[YPT], bi2[YPT];
#pragma unroll
    for (int u = 0; u < YPT; ++u) {
        bd0[u] = 1e30f; bd1[u] = 1e30f; bd2[u] = 1e30f;
        bi0[u] = 0; bi1[u] = 0; bi2[u] = 0;
    }

    int gbase = chunk * KCS;
#pragma unroll 4
    for (int i = 0; i < KCS; i += 4) {
        float4 s[4];
#pragma unroll
        for (int v = 0; v < 4; ++v) s[v] = sx[i + v];
#pragma unroll
        for (int v = 0; v < 4; ++v) {
            int gi = gbase + i + v;
#pragma unroll
            for (int u = 0; u < YPT; ++u) {
                float t = fmaf(m2y[u][0], s[v].x, s[v].w);
                t = fmaf(m2y[u][1], s[v].y, t);
                t = fmaf(m2y[u][2], s[v].z, t);
                t += sy[u];
                bool c0 = t < bd0[u];
                bool c1 = t < bd1[u];
                bool c2 = t < bd2[u];
                float n0 = fminf(bd0[u], t);
                float n1 = __builtin_amdgcn_fmed3f(bd0[u], bd1[u], t);
                float n2 = __builtin_amdgcn_fmed3f(bd1[u], bd2[u], t);
                int j0 = c0 ? gi : bi0[u];
                int j1 = c0 ? bi0[u] : (c1 ? gi : bi1[u]);
                int j2 = c1 ? bi1[u] : (c2 ? gi : bi2[u]);
                bd0[u] = n0; bd1[u] = n1; bd2[u] = n2;
                bi0[u] = j0; bi1[u] = j1; bi2[u] = j2;
            }
        }
    }
#pragma unroll
    for (int u = 0; u < YPT; ++u) {
        int y = ybase + u * 256;
        int base = (chunk * N1 + y) * 3;
        pb_d[base] = bd0[u]; pb_d[base + 1] = bd1[u]; pb_d[base + 2] = bd2[u];
        pb_i[base] = bi0[u]; pb_i[base + 1] = bi1[u]; pb_i[base + 2] = bi2[u];
    }
}

__global__ __launch_bounds__(256)
void knn_merge_kernel(const float* __restrict__ pb_d, const int* __restrict__ pb_i,
                      int* __restrict__ knn_idx, float* __restrict__ knn_w) {
    int y = blockIdx.x * 256 + threadIdx.x;
    float bd0 = 1e30f, bd1 = 1e30f, bd2 = 1e30f;
    int bi0 = 0, bi1 = 0, bi2 = 0;
    for (int c = 0; c < KCH; ++c) {
        int base = (c * N1 + y) * 3;
#pragma unroll
        for (int t3 = 0; t3 < 3; ++t3) {
            float t = pb_d[base + t3];
            int gi = pb_i[base + t3];
            bool c0 = t < bd0;
            bool c1 = t < bd1;
            bool c2 = t < bd2;
            float n0 = fminf(bd0, t);
            float n1 = __builtin_amdgcn_fmed3f(bd0, bd1, t);
            float n2 = __builtin_amdgcn_fmed3f(bd1, bd2, t);
            int j0 = c0 ? gi : bi0;
            int j1 = c0 ? bi0 : (c1 ? gi : bi1);
            int j2 = c1 ? bi1 : (c2 ? gi : bi2);
            bd0 = n0; bd1 = n1; bd2 = n2;
            bi0 = j0; bi1 = j1; bi2 = j2;
        }
    }
    knn_idx[y * 3]     = bi0;
    knn_idx[y * 3 + 1] = bi1;
    knn_idx[y * 3 + 2] = bi2;
    knn_w[y * 3]     = 1.0f / fmaxf(bd0, 1e-16f);
    knn_w[y * 3 + 1] = 1.0f / fmaxf(bd1, 1e-16f);
    knn_w[y * 3 + 2] = 1.0f / fmaxf(bd2, 1e-16f);
}

// ---------------------------------------------------------------------------
// interp: writes bf16 A-fragments for layer-2 GEMM directly.
// ---------------------------------------------------------------------------
__global__ __launch_bounds__(256)
void interp_kernel(const float* __restrict__ x0, const int* __restrict__ knn_idx,
                   const float* __restrict__ knn_w, unsigned short* __restrict__ hswz) {
    int wave = threadIdx.x >> 6;
    int lane = threadIdx.x & 63;
    int y = blockIdx.x * 4 + wave;
    int i0 = 2 * lane;
    float w0 = knn_w[y * 3], w1 = knn_w[y * 3 + 1], w2 = knn_w[y * 3 + 2];
    int j0 = knn_idx[y * 3], j1 = knn_idx[y * 3 + 1], j2 = knn_idx[y * 3 + 2];
    float inv = 1.0f / (w0 + w1 + w2);
    float2 a = *(const float2*)&x0[(size_t)j0 * 128 + i0];
    float2 b = *(const float2*)&x0[(size_t)j1 * 128 + i0];
    float2 c = *(const float2*)&x0[(size_t)j2 * 128 + i0];
    float rx = (w0 * a.x + w1 * b.x + w2 * c.x) * inv;
    float ry = (w0 * a.y + w1 * b.y + w2 * c.y) * inv;
    unsigned int packed = (unsigned int)f2bf(rx) | ((unsigned int)f2bf(ry) << 16);
    int g = i0 >> 5, sub = (i0 >> 3) & 3, jj = i0 & 7;
    size_t idx = (size_t)((((y >> 4) * 5 + g) * 64) + sub * 16 + (y & 15)) * 8 + jj;
    *(unsigned int*)&hswz[idx] = packed;
}

// ---------------------------------------------------------------------------
// Output head: out[y] = [x1[y] | pos1[y]] @ out_W.T + out_b. One wave per y.
// ---------------------------------------------------------------------------
__global__ __launch_bounds__(256)
void out_kernel(const float* __restrict__ x1, const float* __restrict__ pos1,
                const float* __restrict__ W, const float* __restrict__ b,
                float* __restrict__ out) {
    int wave = threadIdx.x >> 6;
    int lane = threadIdx.x & 63;
    int y = blockIdx.x * 4 + wave;
    float h0 = x1[(size_t)y * 128 + lane];
    float h1 = x1[(size_t)y * 128 + 64 + lane];
    float acc[3];
#pragma unroll
    for (int o = 0; o < 3; ++o) {
        float p = h0 * W[o * 131 + lane] + h1 * W[o * 131 + 64 + lane];
#pragma unroll
        for (int off = 1; off < 64; off <<= 1) p += __shfl_xor(p, off, 64);
        acc[o] = p;
    }
    if (lane == 0) {
        float p0 = pos1[y * 3], p1 = pos1[y * 3 + 1], p2 = pos1[y * 3 + 2];
#pragma unroll
        for (int o = 0; o < 3; ++o) {
            out[y * 3 + o] = acc[o] + b[o] + p0 * W[o * 131 + 128]
                           + p1 * W[o * 131 + 129] + p2 * W[o * 131 + 130];
        }
    }
}

// ---------------------------------------------------------------------------
extern "C" void kernel_launch(void* const* d_in, const int* in_sizes, int n_in,
                              void* d_out, int out_size, void* d_ws, size_t ws_size,
                              hipStream_t stream) {
    (void)in_sizes; (void)n_in; (void)out_size; (void)ws_size;
    const float* latent   = (const float*)d_in[0];
    const float* pos0     = (const float*)d_in[1];
    const float* pos1     = (const float*)d_in[2];
    const float* conv_Wl  = (const float*)d_in[5];
    const float* conv_bl  = (const float*)d_in[6];
    const float* conv_Wr  = (const float*)d_in[7];
    const float* conv_br  = (const float*)d_in[8];
    const float* conv_We  = (const float*)d_in[9];
    const float* conv_att = (const float*)d_in[10];
    const float* conv_bias= (const float*)d_in[11];
    const float* lin0_W   = (const float*)d_in[12];
    const float* lin0_b   = (const float*)d_in[13];
    const float* lins_W   = (const float*)d_in[14];
    const float* lins_b   = (const float*)d_in[15];
    const float* out_W    = (const float*)d_in[16];
    const float* out_b    = (const float*)d_in[17];
    float* out = (float*)d_out;

    char* ws = (char*)d_ws;
    unsigned short* Wswz = (unsigned short*)ws; ws += (size_t)4 * WSWZ_PER_LAYER * 2;
    float* bias_cat = (float*)ws;  ws += (size_t)4 * JTOT * 4;
    float* Wt0      = (float*)ws;  ws += (size_t)64 * 128 * 4;
    unsigned short* hswz0A = (unsigned short*)ws; ws += (size_t)(N0 / 16) * NG * 64 * 8 * 2;
    unsigned short* hswz0B = (unsigned short*)ws; ws += (size_t)(N0 / 16) * NG * 64 * 8 * 2;
    unsigned short* hswz1A = (unsigned short*)ws; ws += (size_t)(N1 / 16) * NG * 64 * 8 * 2;
    unsigned short* hswz1B = (unsigned short*)ws; ws += (size_t)(N1 / 16) * NG * 64 * 8 * 2;
    float* bufA     = (float*)ws;  ws += (size_t)N0 * 128 * 4;
    float* bufB     = (float*)ws;  ws += (size_t)N1 * 128 * 4;
    float* linb     = (float*)ws;  ws += (size_t)N1 * 128 * 4;   // lin scratch
    float* pb_d     = (float*)ws;  ws += (size_t)KCH * N1 * 3 * 4;
    int*   pb_i     = (int*)ws;    ws += (size_t)KCH * N1 * 3 * 4;
    int*   knn_idx  = (int*)ws;    ws += (size_t)N1 * 3 * 4;
    float* knn_w    = (float*)ws;  ws += (size_t)N1 * 3 * 4;

    prep_kernel<<<3880, 256, 0, stream>>>(conv_Wl, conv_Wr, conv_We, lins_W,
                                          conv_bl, conv_br, lins_b, lin0_W,
                                          pos0, pos1,
                                          Wswz, bias_cat, Wt0,
                                          hswz0A, hswz0B, hswz1A, hswz1B);
    lin0_kernel<<<N0, 128, 0, stream>>>(latent, Wt0, lin0_b, hswz0A);

    // knn chain is independent - launch early
    knn_part_kernel<<<dim3(N1 / (256 * YPT), KCH), 256, 0, stream>>>(pos0, pos1, pb_d, pb_i);
    knn_merge_kernel<<<N1 / 256, 256, 0, stream>>>(pb_d, pb_i, knn_idx, knn_w);

    // layer 0: A -> B (bf16 frags);  layer 1: B -> bufA (f32)
    fused_layer_kernel<<<N0 / 16, 256, 0, stream>>>(
        hswz0A, Wswz + (size_t)0 * WSWZ_PER_LAYER, bias_cat + 0 * JTOT,
        conv_att + 0 * 128, conv_bias + 0 * 128, linb, nullptr, hswz0B, 1, N0);
    fused_layer_kernel<<<N0 / 16, 256, 0, stream>>>(
        hswz0B, Wswz + (size_t)1 * WSWZ_PER_LAYER, bias_cat + 1 * JTOT,
        conv_att + 1 * 128, conv_bias + 1 * 128, linb, bufA, nullptr, 0, N0);

    interp_kernel<<<N1 / 4, 256, 0, stream>>>(bufA, knn_idx, knn_w, hswz1A);

    // layer 2: A -> B;  layer 3: B -> bufB (f32)
    fused_layer_kernel<<<N1 / 16, 256, 0, stream>>>(
        hswz1A, Wswz + (size_t)2 * WSWZ_PER_LAYER, bias_cat + 2 * JTOT,
        conv_att + 2 * 128, conv_bias + 2 * 128, linb, nullptr, hswz1B, 1, N1);
    fused_layer_kernel<<<N1 / 16, 256, 0, stream>>>(
        hswz1B, Wswz + (size_t)3 * WSWZ_PER_LAYER, bias_cat + 3 * JTOT,
        conv_att + 3 * 128, conv_bias + 3 * 128, linb, bufB, nullptr, 0, N1);

    out_kernel<<<N1 / 4, 256, 0, stream>>>(bufB, pos1, out_W, out_b, out);
}